// Round 4
// baseline (2462.908 us; speedup 1.0000x reference)
//
#include <hip/hip_runtime.h>
#include <math.h>

#define BB 32
#define TT 24
#define NN 256
#define FF 16
#define HH 128
#define G4 512  // 4*H

typedef _Float16 half8 __attribute__((ext_vector_type(8)));
typedef float f32x4 __attribute__((ext_vector_type(4)));

__device__ __forceinline__ float sigf(float x) { return 1.f / (1.f + __expf(-x)); }
__device__ __forceinline__ float tanhfast(float x) { return 1.f - 2.f / (__expf(2.f * x) + 1.f); }

// fp32 -> (hi, lo) fp16 split: v ~= hi + lo, residual ~2^-22 relative.
__device__ __forceinline__ void split8(const float* v, half8& hi, half8& lo) {
#pragma unroll
  for (int i = 0; i < 8; ++i) {
    const _Float16 h = (_Float16)v[i];
    hi[i] = h;
    lo[i] = (_Float16)(v[i] - (float)h);
  }
}

// ---------------------------------------------------------------------------
// K0: pre-split+swizzle gcn_W into B-frag tiles (verified round 3) + zero the
// barrier counters (block 0).
// Wfrag[kc(5)][ct(32)][lane][8]: element W_op[k][n]:
//   kc<4 : gcnW[16 + kc*32 + k][ct*16 + n]; kc==4: k<16 ? gcnW[k][...] : 0
// with k = (lane>>4)*8 + j, n = lane&15.
// ---------------------------------------------------------------------------
__global__ __launch_bounds__(64) void k0_wswz(const float* __restrict__ gcnW,
                                              _Float16* __restrict__ WfH,
                                              _Float16* __restrict__ WfL,
                                              unsigned* __restrict__ cnt) {
  if (blockIdx.x == 0) {
#pragma unroll
    for (int i = 0; i < 8; ++i) cnt[threadIdx.x + 64 * i] = 0u;
  }
  const int bid = blockIdx.x;  // kc*32 + ct, 0..159
  const int kc = bid >> 5, ct = bid & 31;
  const int l = threadIdx.x, quad = l >> 4, lo16 = l & 15;
  float v[8];
#pragma unroll
  for (int j = 0; j < 8; ++j) {
    const int k = quad * 8 + j;
    float val = 0.f;
    if (kc < 4) val = gcnW[(size_t)(16 + kc * 32 + k) * G4 + ct * 16 + lo16];
    else if (k < 16) val = gcnW[(size_t)k * G4 + ct * 16 + lo16];
    v[j] = val;
  }
  half8 hi, lo;
  split8(v, hi, lo);
  const size_t off = (size_t)bid * 512 + l * 8;
  *(half8*)&WfH[off] = hi;
  *(half8*)&WfL[off] = lo;
}

// ---------------------------------------------------------------------------
// Fused GCN-LSTM: 512 blocks x 256 thr, persistent over all T=24 steps.
// block (b, nt): rows n0 = nt*16 .. n0+15 of batch b.
//  prologue: A-frags (regs, from adj), Ax[t] via MFMA -> LDS, bias+c in regs.
//  per step: phase A Ah = A@h (h-frags from global, skip t=0);
//            phase B gates = [Ah|Ax|0] @ Wfrag (W from L2);
//            pointwise LSTM in regs; h -> LDS -> fp16-split frags -> global;
//            per-b group barrier (16 blocks, generation counter).
// LDS: one exact 74368-B blob (Ah 16x132 | gates 16x516 | hst 16x130 |
//      Ax 24x256) => 2 blocks/CU guaranteed with __launch_bounds__(256,2);
//      grid 512 = 2/CU on 256 CUs -> all blocks co-resident (barrier-safe).
// ---------------------------------------------------------------------------
#define AH_OFF 0        // 16*132 = 2112
#define GS_OFF 2112     // 16*516 = 8256
#define HS_OFF 10368    // 16*130 = 2080
#define AX_OFF 12448    // 24*256 = 6144
#define SMEM_F 18592    // total floats = 74368 B

__global__ __launch_bounds__(256, 2) void k_fused(
    const float* __restrict__ adj, const float* __restrict__ x,
    const _Float16* __restrict__ WfH, const _Float16* __restrict__ WfL,
    const float* __restrict__ gcnb, _Float16* __restrict__ hfH0,
    _Float16* __restrict__ hfL0, _Float16* __restrict__ hfH1,
    _Float16* __restrict__ hfL1, float* __restrict__ h32,
    unsigned* __restrict__ cnt) {
  const int bid = blockIdx.x;
  const int b = bid >> 4, nt = bid & 15;
  const int n0 = nt * 16;
  const int tid = threadIdx.x;
  const int w = tid >> 6, l = tid & 63, quad = l >> 4, lo16 = l & 15;

  __shared__ float smem[SMEM_F];
  float* Ah_s = smem + AH_OFF;
  float* g_s = smem + GS_OFF;
  float* hst = smem + HS_OFF;
  float* Ax_s = smem + AX_OFF;

  // ---- prologue: A-frags into registers (rows n0+lo16, k = kc*32+quad*8+j) ----
  half8 afH[8], afL[8];
  {
    const float* Abase = adj + ((size_t)(b * TT + TT - 1) * NN + n0 + lo16) * NN;
#pragma unroll
    for (int kc = 0; kc < 8; ++kc) {
      const float4 p0 = *(const float4*)(Abase + kc * 32 + quad * 8);
      const float4 p1 = *(const float4*)(Abase + kc * 32 + quad * 8 + 4);
      float v[8] = {p0.x, p0.y, p0.z, p0.w, p1.x, p1.y, p1.z, p1.w};
      split8(v, afH[kc], afL[kc]);
    }
  }
  // bias in regs (pointwise mapping: node = tid>>4, cols colg..colg+7)
  const int node = tid >> 4, colg = (tid & 15) * 8;
  float bia[4][8];
#pragma unroll
  for (int g = 0; g < 4; ++g) {
    *(float4*)&bia[g][0] = *(const float4*)&gcnb[g * HH + colg];
    *(float4*)&bia[g][4] = *(const float4*)&gcnb[g * HH + colg + 4];
  }
  float c[8];
#pragma unroll
  for (int j = 0; j < 8; ++j) c[j] = 0.f;

  // ---- prologue: Ax[t] = A_rows @ x[b,t]  (wave w does t = w, w+4, ...) ----
  for (int t = w; t < TT; t += 4) {
    f32x4 acc = (f32x4){0.f, 0.f, 0.f, 0.f};
    const float* xb = x + ((size_t)(b * TT + t)) * NN * FF;
    for (int kc = 0; kc < 8; ++kc) {
      float v[8];
#pragma unroll
      for (int j = 0; j < 8; ++j) v[j] = xb[(kc * 32 + quad * 8 + j) * FF + lo16];
      half8 xH, xL;
      split8(v, xH, xL);
      acc = __builtin_amdgcn_mfma_f32_16x16x32_f16(afL[kc], xH, acc, 0, 0, 0);
      acc = __builtin_amdgcn_mfma_f32_16x16x32_f16(afH[kc], xL, acc, 0, 0, 0);
      acc = __builtin_amdgcn_mfma_f32_16x16x32_f16(afH[kc], xH, acc, 0, 0, 0);
    }
#pragma unroll
    for (int r = 0; r < 4; ++r) Ax_s[t * 256 + (quad * 4 + r) * 16 + lo16] = acc[r];
  }
  __syncthreads();

  const size_t hfbase = (size_t)b * 64 * 512;

  for (int t = 0; t < TT; ++t) {
    // ---- phase A: Ah = A @ h (wave w -> hcol tiles 2w, 2w+1) ----
    f32x4 accA[2];
    accA[0] = (f32x4){0.f, 0.f, 0.f, 0.f};
    accA[1] = (f32x4){0.f, 0.f, 0.f, 0.f};
    if (t > 0) {
      const _Float16* hH = (t & 1) ? hfH1 : hfH0;
      const _Float16* hL = (t & 1) ? hfL1 : hfL0;
      for (int kc = 0; kc < 8; ++kc) {
        const size_t o0 = hfbase + ((size_t)kc * 8 + 2 * w) * 512 + l * 8;
        const half8 bH0 = *(const half8*)&hH[o0];
        const half8 bL0 = *(const half8*)&hL[o0];
        const half8 bH1 = *(const half8*)&hH[o0 + 512];
        const half8 bL1 = *(const half8*)&hL[o0 + 512];
        accA[0] = __builtin_amdgcn_mfma_f32_16x16x32_f16(afL[kc], bH0, accA[0], 0, 0, 0);
        accA[0] = __builtin_amdgcn_mfma_f32_16x16x32_f16(afH[kc], bL0, accA[0], 0, 0, 0);
        accA[0] = __builtin_amdgcn_mfma_f32_16x16x32_f16(afH[kc], bH0, accA[0], 0, 0, 0);
        accA[1] = __builtin_amdgcn_mfma_f32_16x16x32_f16(afL[kc], bH1, accA[1], 0, 0, 0);
        accA[1] = __builtin_amdgcn_mfma_f32_16x16x32_f16(afH[kc], bL1, accA[1], 0, 0, 0);
        accA[1] = __builtin_amdgcn_mfma_f32_16x16x32_f16(afH[kc], bH1, accA[1], 0, 0, 0);
      }
    }
#pragma unroll
    for (int cc = 0; cc < 2; ++cc)
#pragma unroll
      for (int r = 0; r < 4; ++r)
        Ah_s[(quad * 4 + r) * 132 + (2 * w + cc) * 16 + lo16] = accA[cc][r];
    __syncthreads();  // B1: Ah ready

    // ---- phase B: gates = [Ah|Ax|0] @ W (wave w -> gate cols w*128..+127) ----
    f32x4 acc[8];
#pragma unroll
    for (int cc = 0; cc < 8; ++cc) acc[cc] = (f32x4){0.f, 0.f, 0.f, 0.f};
    for (int kc = 0; kc < 5; ++kc) {
      half8 aH, aL;
      if (kc < 4) {
        const float* src = &Ah_s[lo16 * 132 + kc * 32 + quad * 8];
        const float4 p0 = *(const float4*)src;
        const float4 p1 = *(const float4*)(src + 4);
        float v[8] = {p0.x, p0.y, p0.z, p0.w, p1.x, p1.y, p1.z, p1.w};
        split8(v, aH, aL);
      } else {
        float v[8];
        if (quad < 2) {
#pragma unroll
          for (int j = 0; j < 8; ++j) v[j] = Ax_s[t * 256 + lo16 * 16 + quad * 8 + j];
        } else {
#pragma unroll
          for (int j = 0; j < 8; ++j) v[j] = 0.f;
        }
        split8(v, aH, aL);
      }
#pragma unroll
      for (int cc = 0; cc < 8; ++cc) {
        const size_t wo = ((size_t)(kc * 32 + w * 8 + cc)) * 512 + l * 8;
        const half8 wH = *(const half8*)&WfH[wo];
        const half8 wL = *(const half8*)&WfL[wo];
        acc[cc] = __builtin_amdgcn_mfma_f32_16x16x32_f16(aL, wH, acc[cc], 0, 0, 0);
        acc[cc] = __builtin_amdgcn_mfma_f32_16x16x32_f16(aH, wL, acc[cc], 0, 0, 0);
        acc[cc] = __builtin_amdgcn_mfma_f32_16x16x32_f16(aH, wH, acc[cc], 0, 0, 0);
      }
    }
    // C-write gates (g_s distinct from Ah_s; prior g_s readers done at B4 of t-1)
#pragma unroll
    for (int cc = 0; cc < 8; ++cc)
#pragma unroll
      for (int r = 0; r < 4; ++r)
        g_s[(quad * 4 + r) * 516 + (w * 8 + cc) * 16 + lo16] = acc[cc][r];
    __syncthreads();  // B3: gates ready (also: Ah reads done)

    // ---- pointwise LSTM (c in regs) ----
    float hv[8];
#pragma unroll
    for (int j = 0; j < 8; ++j) {
      const float gi = g_s[node * 516 + 0 * HH + colg + j] + bia[0][j];
      const float gf = g_s[node * 516 + 1 * HH + colg + j] + bia[1][j];
      const float gg = g_s[node * 516 + 2 * HH + colg + j] + bia[2][j];
      const float go = g_s[node * 516 + 3 * HH + colg + j] + bia[3][j];
      const float cn = sigf(gf) * c[j] + sigf(gi) * tanhfast(gg);
      c[j] = cn;
      hv[j] = sigf(go) * tanhfast(cn);
    }
#pragma unroll
    for (int j = 0; j < 8; ++j) hst[node * 130 + colg + j] = hv[j];
    if (t == TT - 1) {
      float* dst = &h32[((size_t)b * NN + n0 + node) * HH + colg];
      *(float4*)dst = make_float4(hv[0], hv[1], hv[2], hv[3]);
      *(float4*)(dst + 4) = make_float4(hv[4], hv[5], hv[6], hv[7]);
    }
    __syncthreads();  // B4: hst ready, g_s reads done

    // ---- h-frag production (this block owns half of kc = nt>>1) ----
    if (t < TT - 1) {
      _Float16* oH = (t & 1) ? hfH0 : hfH1;  // buffer (t+1)&1
      _Float16* oL = (t & 1) ? hfL0 : hfL1;
      if ((l >> 5) == (nt & 1)) {
        const int kq = quad - 2 * (nt & 1);  // 0 or 1
#pragma unroll
        for (int cc = 0; cc < 2; ++cc) {
          const int ct = 2 * w + cc;
          float v[8];
#pragma unroll
          for (int j = 0; j < 8; ++j) v[j] = hst[(kq * 8 + j) * 130 + ct * 16 + lo16];
          half8 hh, hl;
          split8(v, hh, hl);
          const size_t o = hfbase + ((size_t)(nt >> 1) * 8 + ct) * 512 + l * 8;
          *(half8*)&oH[o] = hh;
          *(half8*)&oL[o] = hl;
        }
      }
      __syncthreads();  // drain hf stores (vmcnt) from all waves before release
      if (tid == 0) {
        __threadfence();
        __hip_atomic_fetch_add(&cnt[b * 16], 1u, __ATOMIC_SEQ_CST, __HIP_MEMORY_SCOPE_AGENT);
        const unsigned tgt = 16u * (unsigned)(t + 1);
        while (__hip_atomic_load(&cnt[b * 16], __ATOMIC_SEQ_CST, __HIP_MEMORY_SCOPE_AGENT) < tgt) {
          __builtin_amdgcn_s_sleep(2);
        }
        __threadfence();
      }
      __syncthreads();  // all threads see the new h-frags
    }
  }
}

// ---------------------------------------------------------------------------
// Tail: GRU over t + fc5/fc2/fc3/fc4. grid = B, 384 threads. (round-3 verified)
// ---------------------------------------------------------------------------
__global__ __launch_bounds__(384) void k_tail(
    const float* __restrict__ x, const float* __restrict__ h32,
    const int* __restrict__ tsi_p, const float* __restrict__ gruWih,
    const float* __restrict__ gruWhh, const float* __restrict__ gru_bih,
    const float* __restrict__ gru_bhh, const float* __restrict__ fc2W,
    const float* __restrict__ fc2b, const float* __restrict__ fc3W,
    const float* __restrict__ fc3b, const float* __restrict__ fc4W,
    const float* __restrict__ fc4b, const float* __restrict__ fc5W,
    const float* __restrict__ fc5b, float* __restrict__ out) {
  const int b = blockIdx.x;
  const int m = threadIdx.x;
  const int tsi = tsi_p[0];

  __shared__ float h_s[HH];
  __shared__ float xts[TT * FF];
  __shared__ float sum_s[384];
  __shared__ float gh_s[384];
  __shared__ float hc_s[2 * HH];
  __shared__ float xr_s[HH];
  __shared__ float f2_s[HH];
  __shared__ float f3_s[64];

  float4 whh[32];
#pragma unroll
  for (int q = 0; q < 32; ++q) whh[q] = *(const float4*)&gruWhh[(size_t)m * HH + q * 4];
  float4 wih[4];
#pragma unroll
  for (int q = 0; q < 4; ++q) wih[q] = *(const float4*)&gruWih[(size_t)m * FF + q * 4];
  const float bih_r = gru_bih[m];
  const float bhh_r = gru_bhh[m];

  {
    const int t = m >> 4, f = m & 15;
    xts[m] = x[(((size_t)b * TT + t) * NN + tsi) * FF + f];
  }
  if (m < HH) h_s[m] = 0.f;
  __syncthreads();

  for (int t = 0; t < TT; ++t) {
    float gi = bih_r;
#pragma unroll
    for (int q = 0; q < 4; ++q) {
      const float4 xv = *(const float4*)&xts[t * FF + q * 4];
      gi += wih[q].x * xv.x + wih[q].y * xv.y + wih[q].z * xv.z + wih[q].w * xv.w;
    }
    float gh = bhh_r;
#pragma unroll
    for (int q = 0; q < 32; ++q) {
      const float4 hv = *(const float4*)&h_s[q * 4];
      gh += whh[q].x * hv.x + whh[q].y * hv.y + whh[q].z * hv.z + whh[q].w * hv.w;
    }
    sum_s[m] = gi + gh;
    gh_s[m] = gh;
    __syncthreads();
    float hnew = 0.f;
    if (m < HH) {
      const float r = sigf(sum_s[m]);
      const float z = sigf(sum_s[HH + m]);
      const float ghn = gh_s[2 * HH + m];
      const float nn = tanhfast(sum_s[2 * HH + m] - ghn + r * ghn);
      hnew = (1.f - z) * nn + z * h_s[m];
    }
    __syncthreads();
    if (m < HH) h_s[m] = hnew;
    __syncthreads();
  }

  if (m < HH) {
    hc_s[m] = h_s[m];
    xr_s[m] = fmaxf(h32[((size_t)b * NN + tsi) * HH + m], 0.f);
  }
  __syncthreads();
  if (m < HH) {
    float v = fc5b[m];
    const float* wr = fc5W + (size_t)m * HH;
#pragma unroll 8
    for (int k = 0; k < HH; k += 4) {
      const float4 wv = *(const float4*)(wr + k);
      v += xr_s[k] * wv.x + xr_s[k + 1] * wv.y + xr_s[k + 2] * wv.z + xr_s[k + 3] * wv.w;
    }
    hc_s[HH + m] = v;
  }
  __syncthreads();
  if (m < HH) {
    float v = fc2b[m];
    const float* wr = fc2W + (size_t)m * 2 * HH;
#pragma unroll 8
    for (int k = 0; k < 2 * HH; k += 4) {
      const float4 wv = *(const float4*)(wr + k);
      v += hc_s[k] * wv.x + hc_s[k + 1] * wv.y + hc_s[k + 2] * wv.z + hc_s[k + 3] * wv.w;
    }
    f2_s[m] = fmaxf(v, 0.f);
  }
  __syncthreads();
  if (m < 64) {
    float v = fc3b[m];
    const float* wr = fc3W + (size_t)m * HH;
#pragma unroll 8
    for (int k = 0; k < HH; k += 4) {
      const float4 wv = *(const float4*)(wr + k);
      v += f2_s[k] * wv.x + f2_s[k + 1] * wv.y + f2_s[k + 2] * wv.z + f2_s[k + 3] * wv.w;
    }
    f3_s[m] = fmaxf(v, 0.f);
  }
  __syncthreads();
  if (m < 24) {
    float v = fc4b[m];
    const float* wr = fc4W + (size_t)m * 64;
#pragma unroll
    for (int k = 0; k < 64; k += 4) {
      const float4 wv = *(const float4*)(wr + k);
      v += f3_s[k] * wv.x + f3_s[k + 1] * wv.y + f3_s[k + 2] * wv.z + f3_s[k + 3] * wv.w;
    }
    out[b * 24 + m] = v;
  }
}

// ---------------------------------------------------------------------------
extern "C" void kernel_launch(void* const* d_in, const int* in_sizes, int n_in,
                              void* d_out, int out_size, void* d_ws, size_t ws_size,
                              hipStream_t stream) {
  const float* x = (const float*)d_in[0];
  const float* adj = (const float*)d_in[1];
  const int* tsi = (const int*)d_in[2];
  const float* gcnW = (const float*)d_in[3];
  const float* gcnb = (const float*)d_in[4];
  const float* gruWih = (const float*)d_in[5];
  const float* gruWhh = (const float*)d_in[6];
  const float* gru_bih = (const float*)d_in[7];
  const float* gru_bhh = (const float*)d_in[8];
  const float* fc2W = (const float*)d_in[9];
  const float* fc2b = (const float*)d_in[10];
  const float* fc3W = (const float*)d_in[11];
  const float* fc3b = (const float*)d_in[12];
  const float* fc4W = (const float*)d_in[13];
  const float* fc4b = (const float*)d_in[14];
  const float* fc5W = (const float*)d_in[15];
  const float* fc5b = (const float*)d_in[16];
  float* out = (float*)d_out;

  // ws layout
  _Float16* WfH = (_Float16*)d_ws;                 // 81,920 h
  _Float16* WfL = WfH + 81920;                     // 81,920 h
  unsigned* cnt = (unsigned*)(WfL + 81920);        // 512 u32 (2 KB)
  _Float16* hfH0 = (_Float16*)(cnt + 512);         // 1,048,576 h each
  _Float16* hfL0 = hfH0 + 1048576;
  _Float16* hfH1 = hfL0 + 1048576;
  _Float16* hfL1 = hfH1 + 1048576;
  float* h32 = (float*)(hfL1 + 1048576);           // 32*256*128 f

  k0_wswz<<<dim3(160), 64, 0, stream>>>(gcnW, WfH, WfL, cnt);
  k_fused<<<dim3(512), 256, 0, stream>>>(adj, x, WfH, WfL, gcnb, hfH0, hfL0, hfH1, hfL1,
                                         h32, cnt);
  k_tail<<<dim3(BB), 384, 0, stream>>>(x, h32, tsi, gruWih, gruWhh, gru_bih, gru_bhh, fc2W,
                                       fc2b, fc3W, fc3b, fc4W, fc4b, fc5W, fc5b, out);
}

// Round 5
// 1121.003 us; speedup vs baseline: 2.1971x; 2.1971x over previous
//
#include <hip/hip_runtime.h>
#include <math.h>

#define BB 32
#define TT 24
#define NN 256
#define FF 16
#define HH 128
#define G4 512  // 4*H

typedef _Float16 half8 __attribute__((ext_vector_type(8)));
typedef float f32x4 __attribute__((ext_vector_type(4)));

__device__ __forceinline__ float sigf(float x) { return 1.f / (1.f + __expf(-x)); }
__device__ __forceinline__ float tanhfast(float x) { return 1.f - 2.f / (__expf(2.f * x) + 1.f); }

// fp32 -> (hi, lo) fp16 split: v ~= hi + lo, residual ~2^-22 relative.
__device__ __forceinline__ void split8(const float* v, half8& hi, half8& lo) {
#pragma unroll
  for (int i = 0; i < 8; ++i) {
    const _Float16 h = (_Float16)v[i];
    hi[i] = h;
    lo[i] = (_Float16)(v[i] - (float)h);
  }
}

// ---------------------------------------------------------------------------
// K0: pre-split+swizzle gcn_W into B-frag tiles + zero barrier counters.
// Wfrag[kc(5)][ct(32)][lane][8]: element W_op[k][n]:
//   kc<4 : gcnW[16 + kc*32 + k][ct*16 + n]; kc==4: k<16 ? gcnW[k][...] : 0
// with k = (lane>>4)*8 + j, n = lane&15.
// ---------------------------------------------------------------------------
__global__ __launch_bounds__(64) void k0_wswz(const float* __restrict__ gcnW,
                                              _Float16* __restrict__ WfH,
                                              _Float16* __restrict__ WfL,
                                              unsigned* __restrict__ cnt) {
  if (blockIdx.x == 0) {
#pragma unroll
    for (int i = 0; i < 8; ++i) cnt[threadIdx.x + 64 * i] = 0u;
  }
  const int bid = blockIdx.x;  // kc*32 + ct, 0..159
  const int kc = bid >> 5, ct = bid & 31;
  const int l = threadIdx.x, quad = l >> 4, lo16 = l & 15;
  float v[8];
#pragma unroll
  for (int j = 0; j < 8; ++j) {
    const int k = quad * 8 + j;
    float val = 0.f;
    if (kc < 4) val = gcnW[(size_t)(16 + kc * 32 + k) * G4 + ct * 16 + lo16];
    else if (k < 16) val = gcnW[(size_t)k * G4 + ct * 16 + lo16];
    v[j] = val;
  }
  half8 hi, lo;
  split8(v, hi, lo);
  const size_t off = (size_t)bid * 512 + l * 8;
  *(half8*)&WfH[off] = hi;
  *(half8*)&WfL[off] = lo;
}

// ---------------------------------------------------------------------------
// Fused GCN-LSTM. grid 256 x 512 thr (8 waves), 1 block/CU (136 KB LDS).
// bid remap: b = bid&31, g = bid>>5 -> rows 32g..32g+31. All 8 blocks of a
// batch share bid%8 -> same XCD under round-robin dispatch (perf heuristic
// only; correctness from device-scope atomics/fences).
// Per step: phase A Ah = A@h (A-frags regs, h-frags global, skip t=0);
//   C->A transpose of [Ah|Ax|0] through LDS into split-fp16 frags;
//   phase B in 2 row-chunks: gates = frag @ W (W-hi in regs, W-lo from L2),
//   pointwise LSTM (c in regs) straight from g_s; h -> hst -> split frags ->
//   global; 8-block generation barrier per step.
// ---------------------------------------------------------------------------
#define ST_OFF 0      // stage  [32][132] = 4224 f
#define FR_OFF 4224   // frags  10 tiles x 1024 halves = 5120 f
#define GS_OFF 9344   // g_s    [16][516] = 8256 f
#define HS_OFF 17600  // hst    [32][132] = 4224 f
#define AX_OFF 21824  // Ax_s   [24][32][16] = 12288 f
#define SMEM_F 34112  // 136448 B

__global__ __launch_bounds__(512, 2) void k_fused(
    const float* __restrict__ adj, const float* __restrict__ x,
    const _Float16* __restrict__ WfH, const _Float16* __restrict__ WfL,
    const float* __restrict__ gcnb, _Float16* __restrict__ hfH0,
    _Float16* __restrict__ hfL0, _Float16* __restrict__ hfH1,
    _Float16* __restrict__ hfL1, float* __restrict__ h32,
    unsigned* __restrict__ cnt) {
  const int bid = blockIdx.x;
  const int b = bid & 31, g = bid >> 5;  // batch, row-group
  const int n0 = g * 32;
  const int tid = threadIdx.x;
  const int w = tid >> 6, l = tid & 63, quad = l >> 4, lo16 = l & 15;
  const int rt = w & 1;       // phase-A row-tile of this wave
  const int cpair = w >> 1;   // phase-A h-col pair 2*cpair, 2*cpair+1

  __shared__ float smem[SMEM_F];
  float* stage = smem + ST_OFF;
  _Float16* frag = (_Float16*)(smem + FR_OFF);
  float* g_s = smem + GS_OFF;
  float* hst = smem + HS_OFF;
  float* Ax_s = smem + AX_OFF;

  // ---- A-frags (rows n0 + rt*16 + lo16) into registers ----
  half8 afH[8], afL[8];
  {
    const float* Abase = adj + ((size_t)(b * TT + TT - 1) * NN + n0 + rt * 16 + lo16) * NN;
#pragma unroll
    for (int kc = 0; kc < 8; ++kc) {
      const float4 p0 = *(const float4*)(Abase + kc * 32 + quad * 8);
      const float4 p1 = *(const float4*)(Abase + kc * 32 + quad * 8 + 4);
      float v[8] = {p0.x, p0.y, p0.z, p0.w, p1.x, p1.y, p1.z, p1.w};
      split8(v, afH[kc], afL[kc]);
    }
  }
  // ---- W hi-frags stationary: wave w owns gate col-tiles w*4..w*4+3 ----
  half8 wfH[5][4];
#pragma unroll
  for (int kc = 0; kc < 5; ++kc)
#pragma unroll
    for (int cc = 0; cc < 4; ++cc)
      wfH[kc][cc] = *(const half8*)&WfH[((size_t)(kc * 32 + w * 4 + cc)) * 512 + l * 8];

  // ---- pointwise mapping: thread -> node (row in 16-chunk), cols cg*4..+3 ----
  const int node = tid & 15, cg = tid >> 4;  // cg 0..31
  float4 bi4 = *(const float4*)&gcnb[0 * HH + cg * 4];
  float4 bf4 = *(const float4*)&gcnb[1 * HH + cg * 4];
  float4 bg4 = *(const float4*)&gcnb[2 * HH + cg * 4];
  float4 bo4 = *(const float4*)&gcnb[3 * HH + cg * 4];
  float c_st[2][4] = {{0.f, 0.f, 0.f, 0.f}, {0.f, 0.f, 0.f, 0.f}};

  // ---- prologue: Ax via MFMA -> Ax_s. wave w: rt rows, t = cpair + 4i ----
  for (int i = 0; i < 6; ++i) {
    const int t = cpair + 4 * i;
    f32x4 acc = (f32x4){0.f, 0.f, 0.f, 0.f};
    const float* xb = x + ((size_t)(b * TT + t)) * NN * FF;
    for (int kc = 0; kc < 8; ++kc) {
      float v[8];
#pragma unroll
      for (int j = 0; j < 8; ++j) v[j] = xb[(kc * 32 + quad * 8 + j) * FF + lo16];
      half8 xH, xL;
      split8(v, xH, xL);
      acc = __builtin_amdgcn_mfma_f32_16x16x32_f16(afL[kc], xH, acc, 0, 0, 0);
      acc = __builtin_amdgcn_mfma_f32_16x16x32_f16(afH[kc], xL, acc, 0, 0, 0);
      acc = __builtin_amdgcn_mfma_f32_16x16x32_f16(afH[kc], xH, acc, 0, 0, 0);
    }
#pragma unroll
    for (int r = 0; r < 4; ++r)
      Ax_s[(t * 32 + rt * 16 + quad * 4 + r) * 16 + lo16] = acc[r];
  }
  __syncthreads();

  const size_t hfbase = (size_t)b * 64 * 512;

  for (int t = 0; t < TT; ++t) {
    // ---- phase A: Ah tiles (rt, 2*cpair + {0,1}) ----
    f32x4 accA[2];
    accA[0] = (f32x4){0.f, 0.f, 0.f, 0.f};
    accA[1] = (f32x4){0.f, 0.f, 0.f, 0.f};
    if (t > 0) {
      const _Float16* hH = (t & 1) ? hfH1 : hfH0;
      const _Float16* hL = (t & 1) ? hfL1 : hfL0;
      for (int kc = 0; kc < 8; ++kc) {
        const size_t o0 = hfbase + ((size_t)kc * 8 + 2 * cpair) * 512 + l * 8;
        const half8 bH0 = *(const half8*)&hH[o0];
        const half8 bL0 = *(const half8*)&hL[o0];
        const half8 bH1 = *(const half8*)&hH[o0 + 512];
        const half8 bL1 = *(const half8*)&hL[o0 + 512];
        accA[0] = __builtin_amdgcn_mfma_f32_16x16x32_f16(afL[kc], bH0, accA[0], 0, 0, 0);
        accA[0] = __builtin_amdgcn_mfma_f32_16x16x32_f16(afH[kc], bL0, accA[0], 0, 0, 0);
        accA[0] = __builtin_amdgcn_mfma_f32_16x16x32_f16(afH[kc], bH0, accA[0], 0, 0, 0);
        accA[1] = __builtin_amdgcn_mfma_f32_16x16x32_f16(afL[kc], bH1, accA[1], 0, 0, 0);
        accA[1] = __builtin_amdgcn_mfma_f32_16x16x32_f16(afH[kc], bL1, accA[1], 0, 0, 0);
        accA[1] = __builtin_amdgcn_mfma_f32_16x16x32_f16(afH[kc], bH1, accA[1], 0, 0, 0);
      }
    }
#pragma unroll
    for (int cc = 0; cc < 2; ++cc)
#pragma unroll
      for (int r = 0; r < 4; ++r)
        stage[(rt * 16 + quad * 4 + r) * 132 + (2 * cpair + cc) * 16 + lo16] = accA[cc][r];
    __syncthreads();  // B1: Ah staged

    // ---- frag-build: [Ah|Ax|0] -> split-fp16 A-frags. tiles tix = frt*5+fkc ----
    for (int task = w; task < 10; task += 8) {
      const int frt = task / 5, fkc = task % 5;
      float v[8];
      if (fkc < 4) {
        const float* src = &stage[(frt * 16 + lo16) * 132 + fkc * 32 + quad * 8];
        const float4 p0 = *(const float4*)src;
        const float4 p1 = *(const float4*)(src + 4);
        v[0] = p0.x; v[1] = p0.y; v[2] = p0.z; v[3] = p0.w;
        v[4] = p1.x; v[5] = p1.y; v[6] = p1.z; v[7] = p1.w;
      } else {
        if (quad < 2) {
#pragma unroll
          for (int j = 0; j < 8; ++j)
            v[j] = Ax_s[(t * 32 + frt * 16 + lo16) * 16 + quad * 8 + j];
        } else {
#pragma unroll
          for (int j = 0; j < 8; ++j) v[j] = 0.f;
        }
      }
      half8 aH, aL;
      split8(v, aH, aL);
      *(half8*)&frag[task * 1024 + l * 8] = aH;
      *(half8*)&frag[task * 1024 + 512 + l * 8] = aL;
    }
    __syncthreads();  // B2: frags ready

    // ---- phase B in 2 row-chunks of 16 ----
    for (int ch = 0; ch < 2; ++ch) {
      f32x4 acc[4];
#pragma unroll
      for (int cc = 0; cc < 4; ++cc) acc[cc] = (f32x4){0.f, 0.f, 0.f, 0.f};
      for (int kc = 0; kc < 5; ++kc) {
        const int tix = ch * 5 + kc;
        const half8 aH = *(const half8*)&frag[tix * 1024 + l * 8];
        const half8 aL = *(const half8*)&frag[tix * 1024 + 512 + l * 8];
#pragma unroll
        for (int cc = 0; cc < 4; ++cc) {
          const half8 wLv =
              *(const half8*)&WfL[((size_t)(kc * 32 + w * 4 + cc)) * 512 + l * 8];
          acc[cc] = __builtin_amdgcn_mfma_f32_16x16x32_f16(aL, wfH[kc][cc], acc[cc], 0, 0, 0);
          acc[cc] = __builtin_amdgcn_mfma_f32_16x16x32_f16(aH, wLv, acc[cc], 0, 0, 0);
          acc[cc] = __builtin_amdgcn_mfma_f32_16x16x32_f16(aH, wfH[kc][cc], acc[cc], 0, 0, 0);
        }
      }
      if (ch == 1) __syncthreads();  // B4: chunk-0 g_s reads done
#pragma unroll
      for (int cc = 0; cc < 4; ++cc)
#pragma unroll
        for (int r = 0; r < 4; ++r)
          g_s[(quad * 4 + r) * 516 + (w * 4 + cc) * 16 + lo16] = acc[cc][r];
      __syncthreads();  // B3/B5: gates ready

      // pointwise LSTM for rows ch*16 + node
      union F4 { float4 v; float a[4]; };
      F4 gi, gf, gg, go, hn;
      gi.v = *(const float4*)&g_s[node * 516 + 0 * HH + cg * 4];
      gf.v = *(const float4*)&g_s[node * 516 + 1 * HH + cg * 4];
      gg.v = *(const float4*)&g_s[node * 516 + 2 * HH + cg * 4];
      go.v = *(const float4*)&g_s[node * 516 + 3 * HH + cg * 4];
      const float* bi = (const float*)&bi4;
      const float* bf = (const float*)&bf4;
      const float* bg = (const float*)&bg4;
      const float* bo = (const float*)&bo4;
#pragma unroll
      for (int e = 0; e < 4; ++e) {
        const float iv = sigf(gi.a[e] + bi[e]);
        const float fv = sigf(gf.a[e] + bf[e]);
        const float gv = tanhfast(gg.a[e] + bg[e]);
        const float ov = sigf(go.a[e] + bo[e]);
        const float cn = fv * c_st[ch][e] + iv * gv;
        c_st[ch][e] = cn;
        hn.a[e] = ov * tanhfast(cn);
      }
      *(float4*)&hst[(ch * 16 + node) * 132 + cg * 4] = hn.v;
      if (t == TT - 1)
        *(float4*)&h32[((size_t)b * NN + n0 + ch * 16 + node) * HH + cg * 4] = hn.v;
    }
    __syncthreads();  // B6: hst complete

    if (t < TT - 1) {
      // ---- h-frag production: wave w -> tile (kc=g, ct=w) ----
      float v[8];
#pragma unroll
      for (int j = 0; j < 8; ++j) v[j] = hst[(quad * 8 + j) * 132 + w * 16 + lo16];
      half8 hh, hl;
      split8(v, hh, hl);
      _Float16* oH = (t & 1) ? hfH0 : hfH1;
      _Float16* oL = (t & 1) ? hfL0 : hfL1;
      const size_t o = hfbase + ((size_t)g * 8 + w) * 512 + l * 8;
      *(half8*)&oH[o] = hh;
      *(half8*)&oL[o] = hl;
      __syncthreads();  // B7: drain frag stores (vmcnt) before release
      if (tid == 0) {
        __threadfence();
        __hip_atomic_fetch_add(&cnt[b * 16], 1u, __ATOMIC_RELEASE, __HIP_MEMORY_SCOPE_AGENT);
        const unsigned tgt = 8u * (unsigned)(t + 1);
        while (__hip_atomic_load(&cnt[b * 16], __ATOMIC_RELAXED, __HIP_MEMORY_SCOPE_AGENT) < tgt) {
          __builtin_amdgcn_s_sleep(4);
        }
        __threadfence();
      }
      __syncthreads();  // B8: all threads see new h-frags
    }
  }
}

// ---------------------------------------------------------------------------
// Tail: GRU over t + fc5/fc2/fc3/fc4. grid = B, 384 threads. (verified)
// ---------------------------------------------------------------------------
__global__ __launch_bounds__(384) void k_tail(
    const float* __restrict__ x, const float* __restrict__ h32,
    const int* __restrict__ tsi_p, const float* __restrict__ gruWih,
    const float* __restrict__ gruWhh, const float* __restrict__ gru_bih,
    const float* __restrict__ gru_bhh, const float* __restrict__ fc2W,
    const float* __restrict__ fc2b, const float* __restrict__ fc3W,
    const float* __restrict__ fc3b, const float* __restrict__ fc4W,
    const float* __restrict__ fc4b, const float* __restrict__ fc5W,
    const float* __restrict__ fc5b, float* __restrict__ out) {
  const int b = blockIdx.x;
  const int m = threadIdx.x;
  const int tsi = tsi_p[0];

  __shared__ float h_s[HH];
  __shared__ float xts[TT * FF];
  __shared__ float sum_s[384];
  __shared__ float gh_s[384];
  __shared__ float hc_s[2 * HH];
  __shared__ float xr_s[HH];
  __shared__ float f2_s[HH];
  __shared__ float f3_s[64];

  float4 whh[32];
#pragma unroll
  for (int q = 0; q < 32; ++q) whh[q] = *(const float4*)&gruWhh[(size_t)m * HH + q * 4];
  float4 wih[4];
#pragma unroll
  for (int q = 0; q < 4; ++q) wih[q] = *(const float4*)&gruWih[(size_t)m * FF + q * 4];
  const float bih_r = gru_bih[m];
  const float bhh_r = gru_bhh[m];

  {
    const int t = m >> 4, f = m & 15;
    xts[m] = x[(((size_t)b * TT + t) * NN + tsi) * FF + f];
  }
  if (m < HH) h_s[m] = 0.f;
  __syncthreads();

  for (int t = 0; t < TT; ++t) {
    float gi = bih_r;
#pragma unroll
    for (int q = 0; q < 4; ++q) {
      const float4 xv = *(const float4*)&xts[t * FF + q * 4];
      gi += wih[q].x * xv.x + wih[q].y * xv.y + wih[q].z * xv.z + wih[q].w * xv.w;
    }
    float gh = bhh_r;
#pragma unroll
    for (int q = 0; q < 32; ++q) {
      const float4 hv = *(const float4*)&h_s[q * 4];
      gh += whh[q].x * hv.x + whh[q].y * hv.y + whh[q].z * hv.z + whh[q].w * hv.w;
    }
    sum_s[m] = gi + gh;
    gh_s[m] = gh;
    __syncthreads();
    float hnew = 0.f;
    if (m < HH) {
      const float r = sigf(sum_s[m]);
      const float z = sigf(sum_s[HH + m]);
      const float ghn = gh_s[2 * HH + m];
      const float nn = tanhfast(sum_s[2 * HH + m] - ghn + r * ghn);
      hnew = (1.f - z) * nn + z * h_s[m];
    }
    __syncthreads();
    if (m < HH) h_s[m] = hnew;
    __syncthreads();
  }

  if (m < HH) {
    hc_s[m] = h_s[m];
    xr_s[m] = fmaxf(h32[((size_t)b * NN + tsi) * HH + m], 0.f);
  }
  __syncthreads();
  if (m < HH) {
    float v = fc5b[m];
    const float* wr = fc5W + (size_t)m * HH;
#pragma unroll 8
    for (int k = 0; k < HH; k += 4) {
      const float4 wv = *(const float4*)(wr + k);
      v += xr_s[k] * wv.x + xr_s[k + 1] * wv.y + xr_s[k + 2] * wv.z + xr_s[k + 3] * wv.w;
    }
    hc_s[HH + m] = v;
  }
  __syncthreads();
  if (m < HH) {
    float v = fc2b[m];
    const float* wr = fc2W + (size_t)m * 2 * HH;
#pragma unroll 8
    for (int k = 0; k < 2 * HH; k += 4) {
      const float4 wv = *(const float4*)(wr + k);
      v += hc_s[k] * wv.x + hc_s[k + 1] * wv.y + hc_s[k + 2] * wv.z + hc_s[k + 3] * wv.w;
    }
    f2_s[m] = fmaxf(v, 0.f);
  }
  __syncthreads();
  if (m < 64) {
    float v = fc3b[m];
    const float* wr = fc3W + (size_t)m * HH;
#pragma unroll 8
    for (int k = 0; k < HH; k += 4) {
      const float4 wv = *(const float4*)(wr + k);
      v += f2_s[k] * wv.x + f2_s[k + 1] * wv.y + f2_s[k + 2] * wv.z + f2_s[k + 3] * wv.w;
    }
    f3_s[m] = fmaxf(v, 0.f);
  }
  __syncthreads();
  if (m < 24) {
    float v = fc4b[m];
    const float* wr = fc4W + (size_t)m * 64;
#pragma unroll
    for (int k = 0; k < 64; k += 4) {
      const float4 wv = *(const float4*)(wr + k);
      v += f3_s[k] * wv.x + f3_s[k + 1] * wv.y + f3_s[k + 2] * wv.z + f3_s[k + 3] * wv.w;
    }
    out[b * 24 + m] = v;
  }
}

// ---------------------------------------------------------------------------
extern "C" void kernel_launch(void* const* d_in, const int* in_sizes, int n_in,
                              void* d_out, int out_size, void* d_ws, size_t ws_size,
                              hipStream_t stream) {
  const float* x = (const float*)d_in[0];
  const float* adj = (const float*)d_in[1];
  const int* tsi = (const int*)d_in[2];
  const float* gcnW = (const float*)d_in[3];
  const float* gcnb = (const float*)d_in[4];
  const float* gruWih = (const float*)d_in[5];
  const float* gruWhh = (const float*)d_in[6];
  const float* gru_bih = (const float*)d_in[7];
  const float* gru_bhh = (const float*)d_in[8];
  const float* fc2W = (const float*)d_in[9];
  const float* fc2b = (const float*)d_in[10];
  const float* fc3W = (const float*)d_in[11];
  const float* fc3b = (const float*)d_in[12];
  const float* fc4W = (const float*)d_in[13];
  const float* fc4b = (const float*)d_in[14];
  const float* fc5W = (const float*)d_in[15];
  const float* fc5b = (const float*)d_in[16];
  float* out = (float*)d_out;

  // ws layout (elements)
  _Float16* WfH = (_Float16*)d_ws;              // 81,920 h
  _Float16* WfL = WfH + 81920;                  // 81,920 h
  unsigned* cnt = (unsigned*)(WfL + 81920);     // 512 u32
  _Float16* hfH0 = (_Float16*)(cnt + 512);      // 1,048,576 h each
  _Float16* hfL0 = hfH0 + 1048576;
  _Float16* hfH1 = hfL0 + 1048576;
  _Float16* hfL1 = hfH1 + 1048576;
  float* h32 = (float*)(hfL1 + 1048576);        // 32*256*128 f

  k0_wswz<<<dim3(160), 64, 0, stream>>>(gcnW, WfH, WfL, cnt);
  k_fused<<<dim3(256), 512, 0, stream>>>(adj, x, WfH, WfL, gcnb, hfH0, hfL0, hfH1, hfL1,
                                         h32, cnt);
  k_tail<<<dim3(BB), 384, 0, stream>>>(x, h32, tsi, gruWih, gruWhh, gru_bih, gru_bhh, fc2W,
                                       fc2b, fc3W, fc3b, fc4W, fc4b, fc5W, fc5b, out);
}